// Round 2
// baseline (1633.118 us; speedup 1.0000x reference)
//
#include <hip/hip_runtime.h>
#include <hip/hip_bf16.h>

typedef __bf16 bf16;
typedef __attribute__((ext_vector_type(8))) __bf16 bf16x8;
typedef __attribute__((ext_vector_type(4))) float f32x4;

#define N_TOK 49
#define HD 32

// ---------------- fp32 -> bf16 weight convert ----------------
__global__ __launch_bounds__(256) void k_f2b(const float* __restrict__ in,
                                             bf16* __restrict__ out, int n) {
    int i = blockIdx.x * 256 + threadIdx.x;
    if (i < n) out[i] = (bf16)in[i];
}

// ---------------- reorder: (B,H,W,C) fp32 -> (win,tok,C) fp32 ----------------
__global__ __launch_bounds__(256) void k_reorder_in(const float* __restrict__ x,
                                                    float* __restrict__ xres) {
    int id = blockIdx.x * 256 + threadIdx.x;          // 19,267,584 total
    int c = id % 384;
    int t = id / 384;
    int b = t / 3136;
    int rem = t - b * 3136;
    int y = rem / 56;
    int xc = rem - y * 56;
    int w = b * 64 + (y / 7) * 8 + (xc / 7);
    int n = (y % 7) * 7 + (xc % 7);
    xres[(size_t)(w * 49 + n) * 384 + c] = x[id];
}

__global__ __launch_bounds__(256) void k_reorder_out(const float* __restrict__ xres,
                                                     float* __restrict__ out) {
    int id = blockIdx.x * 256 + threadIdx.x;
    int c = id % 384;
    int t = id / 384;
    int b = t / 3136;
    int rem = t - b * 3136;
    int y = rem / 56;
    int xc = rem - y * 56;
    int w = b * 64 + (y / 7) * 8 + (xc / 7);
    int n = (y % 7) * 7 + (xc % 7);
    out[id] = xres[(size_t)(w * 49 + n) * 384 + c];
}

// ---------------- LayerNorm: fp32 residual -> bf16 ----------------
__global__ __launch_bounds__(256) void k_ln(const float* __restrict__ xres,
                                            const float* __restrict__ s,
                                            const float* __restrict__ b,
                                            bf16* __restrict__ h) {
    int t = blockIdx.x * 4 + (threadIdx.x >> 6);
    int lane = threadIdx.x & 63;
    const float* row = xres + (size_t)t * 384;
    float v[6];
    float sum = 0.f;
#pragma unroll
    for (int i = 0; i < 6; i++) { v[i] = row[lane + 64 * i]; sum += v[i]; }
#pragma unroll
    for (int m = 1; m < 64; m <<= 1) sum += __shfl_xor(sum, m);
    float mu = sum * (1.f / 384.f);
    float sq = 0.f;
#pragma unroll
    for (int i = 0; i < 6; i++) { float d = v[i] - mu; sq += d * d; }
#pragma unroll
    for (int m = 1; m < 64; m <<= 1) sq += __shfl_xor(sq, m);
    float r = rsqrtf(sq * (1.f / 384.f) + 1e-6f);
    bf16* ho = h + (size_t)t * 384;
#pragma unroll
    for (int i = 0; i < 6; i++) {
        int c = lane + 64 * i;
        ho[c] = (bf16)((v[i] - mu) * r * s[c] + b[c]);
    }
}

// ---------------- GELU (tanh approximation, matches jax.nn.gelu) ----------------
__device__ inline float gelu_f(float x) {
    float u = 0.7978845608028654f * (x + 0.044715f * x * x * x);
    float t = 1.f - 2.f / (__expf(2.f * u) + 1.f);
    return 0.5f * x * (1.f + t);
}

// ---------------- GEMM: C[M,N] = A[M,K] @ B[K,N] (+epilogue) ----------------
// EPI 0: store bf16 | 1: +bias, gelu, store bf16 | 2: add into fp32 resid | 3: +bias, add resid
template <int EPI>
__global__ __launch_bounds__(256) void k_gemm(const bf16* __restrict__ A,
                                              const bf16* __restrict__ B,
                                              const float* __restrict__ bias,
                                              float* __restrict__ resid,
                                              bf16* __restrict__ Cout,
                                              int N, int K) {
    __shared__ __align__(16) bf16 As[128][40];   // +8 pad
    __shared__ __align__(16) bf16 Bs[128][40];   // transposed: Bs[n][k]
    int tid = threadIdx.x;
    int m0 = blockIdx.x * 128;
    int n0 = blockIdx.y * 128;
    int wave = tid >> 6, lane = tid & 63;
    int wm = (wave >> 1) * 64, wn = (wave & 1) * 64;
    int lrow = lane & 15, quad = lane >> 4;

    f32x4 acc[4][4] = {};

    int arow = tid >> 1, aseg = (tid & 1) * 16;
    int bncol = tid & 127, bkg = (tid >> 7) * 16;
    const bf16* Aptr = A + (size_t)(m0 + arow) * K + aseg;
    const bf16* Bptr = B + (size_t)bkg * N + n0 + bncol;

    for (int kb = 0; kb < K; kb += 32) {
        const uint4* ap = (const uint4*)(Aptr + kb);
        uint4 a0 = ap[0];
        uint4 a1 = ap[1];
        bf16 breg[16];
#pragma unroll
        for (int i = 0; i < 16; i++) breg[i] = Bptr[(size_t)(kb + i) * N];
        __syncthreads();
        *(uint4*)&As[arow][aseg] = a0;
        *(uint4*)&As[arow][aseg + 8] = a1;
#pragma unroll
        for (int i = 0; i < 16; i++) Bs[bncol][bkg + i] = breg[i];
        __syncthreads();
        bf16x8 af[4], bfv[4];
#pragma unroll
        for (int i = 0; i < 4; i++)
            af[i] = *(const bf16x8*)&As[wm + i * 16 + lrow][quad * 8];
#pragma unroll
        for (int i = 0; i < 4; i++)
            bfv[i] = *(const bf16x8*)&Bs[wn + i * 16 + lrow][quad * 8];
#pragma unroll
        for (int mi = 0; mi < 4; mi++)
#pragma unroll
            for (int ni = 0; ni < 4; ni++)
                acc[mi][ni] = __builtin_amdgcn_mfma_f32_16x16x32_bf16(
                    af[mi], bfv[ni], acc[mi][ni], 0, 0, 0);
    }

#pragma unroll
    for (int mi = 0; mi < 4; mi++) {
#pragma unroll
        for (int ni = 0; ni < 4; ni++) {
            int gn = n0 + wn + ni * 16 + lrow;
            float bv = 0.f;
            if (EPI == 1 || EPI == 3) bv = bias[gn];
#pragma unroll
            for (int r = 0; r < 4; r++) {
                int gm = m0 + wm + mi * 16 + quad * 4 + r;
                size_t off = (size_t)gm * N + gn;
                float val = acc[mi][ni][r];
                if (EPI == 0) {
                    Cout[off] = (bf16)val;
                } else if (EPI == 1) {
                    Cout[off] = (bf16)gelu_f(val + bv);
                } else if (EPI == 2) {
                    resid[off] += val;
                } else {
                    resid[off] += val + bv;
                }
            }
        }
    }
}

// ---------------- window attention: one block per (window, head) ----------------
__global__ __launch_bounds__(256) void k_attn(const bf16* __restrict__ qkv,
                                              const float* __restrict__ rpb,
                                              bf16* __restrict__ o) {
    int w = blockIdx.x;
    int hh = blockIdx.y;
    __shared__ float qs[N_TOK * HD];
    __shared__ bf16 ks[N_TOK * HD];
    __shared__ bf16 vs[N_TOK * HD];
    __shared__ float S[N_TOK][N_TOK + 1];
    int tid = threadIdx.x;
    const float scale = 0.17677669529663687f;  // 1/sqrt(32)
    const bf16* base = qkv + (size_t)w * 49 * 1152 + hh * 32;

    for (int e = tid; e < 1568; e += 256) {
        int n = e >> 5, d = e & 31;
        size_t row = (size_t)n * 1152 + d;
        qs[e] = (float)base[row] * scale;
        ks[e] = base[row + 384];
        vs[e] = base[row + 768];
    }
    __syncthreads();

    for (int e = tid; e < 2401; e += 256) {
        int i = e / 49, j = e - i * 49;
        const float* qp = qs + i * 32;
        const bf16* kp = ks + j * 32;
        float acc = 0.f;
#pragma unroll 8
        for (int d = 0; d < 32; d++) acc += qp[d] * (float)kp[d];
        int yi = i / 7, xi = i - yi * 7, yj = j / 7, xj = j - yj * 7;
        int idx = (yi - yj + 6) * 13 + (xi - xj + 6);
        S[i][j] = acc + rpb[idx * 12 + hh];
    }
    __syncthreads();

    if (tid < 49) {
        float m = -1e30f;
        for (int j = 0; j < 49; j++) m = fmaxf(m, S[tid][j]);
        float sum = 0.f;
        for (int j = 0; j < 49; j++) {
            float e2 = __expf(S[tid][j] - m);
            S[tid][j] = e2;
            sum += e2;
        }
        float inv = 1.f / sum;
        for (int j = 0; j < 49; j++) S[tid][j] *= inv;
    }
    __syncthreads();

    bf16* ob = o + (size_t)w * 49 * 384 + hh * 32;
    for (int e = tid; e < 1568; e += 256) {
        int i = e >> 5, d = e & 31;
        float acc = 0.f;
        for (int j = 0; j < 49; j++) acc += S[i][j] * (float)vs[j * 32 + d];
        ob[(size_t)i * 384 + d] = (bf16)acc;
    }
}

// ---------------- launch ----------------
extern "C" void kernel_launch(void* const* d_in, const int* in_sizes, int n_in,
                              void* d_out, int out_size, void* d_ws, size_t ws_size,
                              hipStream_t stream) {
    const float* x      = (const float*)d_in[0];
    const float* ln1_s  = (const float*)d_in[1];
    const float* ln1_b  = (const float*)d_in[2];
    const float* qkv_w  = (const float*)d_in[3];
    const float* rpb    = (const float*)d_in[4];
    const float* proj_w = (const float*)d_in[5];
    const float* ln2_s  = (const float*)d_in[6];
    const float* ln2_b  = (const float*)d_in[7];
    const float* mlp_w1 = (const float*)d_in[8];
    const float* mlp_b1 = (const float*)d_in[9];
    const float* mlp_w2 = (const float*)d_in[10];
    const float* mlp_b2 = (const float*)d_in[11];
    float* out = (float*)d_out;

    char* ws = (char*)d_ws;
    float* xres  = (float*)ws;                     // 77,070,336 B
    bf16* qkvbuf = (bf16*)(ws + 77070336);         // 115,605,504 B
    bf16* obuf   = (bf16*)(ws + 192675840);        // 38,535,168 B
    bf16* wbuf   = (bf16*)(ws + 231211008);        // 7,077,888 B (total 238,288,896)
    bf16* hidden = qkvbuf;                         // aliases qkv+obuf (154,140,672 B)
    bf16* hbuf   = (bf16*)d_out;                   // 38.5 MB scratch inside 77 MB out

    bf16* qkvw_b = wbuf;                 // 884,736
    bf16* projw_b = wbuf + 884736;       // 294,912
    bf16* mlp1_b = wbuf + 1179648;       // 1,179,648
    bf16* mlp2_b = wbuf + 2359296;       // 1,179,648

    k_f2b<<<3456, 256, 0, stream>>>(qkv_w, qkvw_b, 884736);
    k_f2b<<<1152, 256, 0, stream>>>(proj_w, projw_b, 294912);
    k_f2b<<<4608, 256, 0, stream>>>(mlp_w1, mlp1_b, 1179648);
    k_f2b<<<4608, 256, 0, stream>>>(mlp_w2, mlp2_b, 1179648);

    k_reorder_in<<<75264, 256, 0, stream>>>(x, xres);

    for (int l = 0; l < 2; l++) {
        k_ln<<<12544, 256, 0, stream>>>(xres, ln1_s + l * 384, ln1_b + l * 384, hbuf);
        k_gemm<0><<<dim3(392, 9), 256, 0, stream>>>(
            hbuf, qkvw_b + (size_t)l * 442368, nullptr, nullptr, qkvbuf, 1152, 384);
        k_attn<<<dim3(1024, 12), 256, 0, stream>>>(qkvbuf, rpb + l * 169 * 12, obuf);
        k_gemm<2><<<dim3(392, 3), 256, 0, stream>>>(
            obuf, projw_b + (size_t)l * 147456, nullptr, xres, nullptr, 384, 384);
        k_ln<<<12544, 256, 0, stream>>>(xres, ln2_s + l * 384, ln2_b + l * 384, hbuf);
        k_gemm<1><<<dim3(392, 12), 256, 0, stream>>>(
            hbuf, mlp1_b + (size_t)l * 589824, mlp_b1 + l * 1536, nullptr, hidden, 1536, 384);
        k_gemm<3><<<dim3(392, 3), 256, 0, stream>>>(
            hidden, mlp2_b + (size_t)l * 589824, mlp_b2 + l * 384, xres, nullptr, 384, 1536);
    }

    k_reorder_out<<<75264, 256, 0, stream>>>(xres, out);
}

// Round 3
// 1466.617 us; speedup vs baseline: 1.1135x; 1.1135x over previous
//
#include <hip/hip_runtime.h>
#include <hip/hip_bf16.h>

typedef __bf16 bf16;
typedef __attribute__((ext_vector_type(4))) __bf16 bf16x4;
typedef __attribute__((ext_vector_type(8))) __bf16 bf16x8;
typedef __attribute__((ext_vector_type(4))) float f32x4;

// ---------------- async global->LDS helper (16B per lane, wave-uniform LDS base) ----
__device__ __forceinline__ void async_ld16(const void* g, void* l) {
    __builtin_amdgcn_global_load_lds(
        (const __attribute__((address_space(1))) unsigned int*)g,
        (__attribute__((address_space(3))) unsigned int*)l, 16, 0, 0);
}

// ---------------- fp32 -> bf16 transposed weight convert: in[K][N] -> out[N][K] ----
__global__ __launch_bounds__(256) void k_f2bt(const float* __restrict__ in,
                                              bf16* __restrict__ out, int Kd, int Nd) {
    int id = blockIdx.x * 256 + threadIdx.x;
    if (id >= Kd * Nd) return;
    int k = id / Nd, n = id - k * Nd;
    out[(size_t)n * Kd + k] = (bf16)in[id];
}

// ---------------- reorder: (B,H,W,C) fp32 <-> (win,tok,C) fp32, float4-wide --------
__global__ __launch_bounds__(256) void k_reorder_in(const float4* __restrict__ x,
                                                    float4* __restrict__ xres) {
    int id = blockIdx.x * 256 + threadIdx.x;          // 4,816,896 float4s
    int c4 = id % 96;
    int t = id / 96;
    int b = t / 3136;
    int rem = t - b * 3136;
    int y = rem / 56;
    int xc = rem - y * 56;
    int w = b * 64 + (y / 7) * 8 + (xc / 7);
    int n = (y % 7) * 7 + (xc % 7);
    xres[(size_t)(w * 49 + n) * 96 + c4] = x[id];
}

__global__ __launch_bounds__(256) void k_reorder_out(const float4* __restrict__ xres,
                                                     float4* __restrict__ out) {
    int id = blockIdx.x * 256 + threadIdx.x;
    int c4 = id % 96;
    int t = id / 96;
    int b = t / 3136;
    int rem = t - b * 3136;
    int y = rem / 56;
    int xc = rem - y * 56;
    int w = b * 64 + (y / 7) * 8 + (xc / 7);
    int n = (y % 7) * 7 + (xc % 7);
    out[id] = xres[(size_t)(w * 49 + n) * 96 + c4];
}

// ---------------- LayerNorm: fp32 residual -> bf16, float4-wide --------------------
__global__ __launch_bounds__(256) void k_ln(const float* __restrict__ xres,
                                            const float* __restrict__ s,
                                            const float* __restrict__ b,
                                            bf16* __restrict__ h) {
    int t = blockIdx.x * 4 + (threadIdx.x >> 6);
    int lane = threadIdx.x & 63;
    const float4* row = (const float4*)(xres + (size_t)t * 384);  // 96 float4
    float4 v0 = row[lane];
    float4 v1 = make_float4(0.f, 0.f, 0.f, 0.f);
    if (lane < 32) v1 = row[64 + lane];
    float sum = v0.x + v0.y + v0.z + v0.w + v1.x + v1.y + v1.z + v1.w;
#pragma unroll
    for (int m = 1; m < 64; m <<= 1) sum += __shfl_xor(sum, m);
    float mu = sum * (1.f / 384.f);
    float sq = (v0.x - mu) * (v0.x - mu) + (v0.y - mu) * (v0.y - mu) +
               (v0.z - mu) * (v0.z - mu) + (v0.w - mu) * (v0.w - mu);
    if (lane < 32)
        sq += (v1.x - mu) * (v1.x - mu) + (v1.y - mu) * (v1.y - mu) +
              (v1.z - mu) * (v1.z - mu) + (v1.w - mu) * (v1.w - mu);
#pragma unroll
    for (int m = 1; m < 64; m <<= 1) sq += __shfl_xor(sq, m);
    float r = rsqrtf(sq * (1.f / 384.f) + 1e-6f);
    const float4* s4 = (const float4*)s;
    const float4* b4 = (const float4*)b;
    bf16* ho = h + (size_t)t * 384;
    {
        float4 sv = s4[lane], bv = b4[lane];
        bf16x4 ov;
        ov[0] = (bf16)((v0.x - mu) * r * sv.x + bv.x);
        ov[1] = (bf16)((v0.y - mu) * r * sv.y + bv.y);
        ov[2] = (bf16)((v0.z - mu) * r * sv.z + bv.z);
        ov[3] = (bf16)((v0.w - mu) * r * sv.w + bv.w);
        *(bf16x4*)&ho[lane * 4] = ov;
    }
    if (lane < 32) {
        float4 sv = s4[64 + lane], bv = b4[64 + lane];
        bf16x4 ov;
        ov[0] = (bf16)((v1.x - mu) * r * sv.x + bv.x);
        ov[1] = (bf16)((v1.y - mu) * r * sv.y + bv.y);
        ov[2] = (bf16)((v1.z - mu) * r * sv.z + bv.z);
        ov[3] = (bf16)((v1.w - mu) * r * sv.w + bv.w);
        *(bf16x4*)&ho[256 + lane * 4] = ov;
    }
}

// ---------------- GELU (tanh approximation, matches jax.nn.gelu) -------------------
__device__ inline float gelu_f(float x) {
    float u = 0.7978845608028654f * (x + 0.044715f * x * x * x);
    float t = 1.f - 2.f / (__expf(2.f * u) + 1.f);
    return 0.5f * x * (1.f + t);
}

// ---------------- GEMM: C[M,N] = A[M,K] @ Bt[N,K]^T (+epilogue) --------------------
// EPI 0: store bf16 | 1: +bias, gelu, store bf16 | 2: add into fp32 resid | 3: +bias, add resid
// 128x128 tile, BK=32, 4 waves (2x2), global_load_lds staging with XOR bank swizzle.
template <int EPI>
__global__ __launch_bounds__(256) void k_gemm(const bf16* __restrict__ A,
                                              const bf16* __restrict__ Bt,
                                              const float* __restrict__ bias,
                                              float* __restrict__ resid,
                                              bf16* __restrict__ Cout,
                                              int N, int K) {
    __shared__ __align__(16) bf16 As[128 * 32];   // [row][k], 8 KB, swizzled ksegs
    __shared__ __align__(16) bf16 Bs[128 * 32];   // [n][k],   8 KB, swizzled ksegs
    int tid = threadIdx.x;
    int m0 = blockIdx.x * 128;
    int n0 = blockIdx.y * 128;
    int wave = tid >> 6, lane = tid & 63;
    int wm = (wave >> 1) * 64, wn = (wave & 1) * 64;
    int lrow = lane & 15, quad = lane >> 4;

    f32x4 acc[4][4] = {};

    // staging: wave handles chunks 2w, 2w+1 of A and B. chunk c = 16 rows x 32 k.
    // lane i -> row = c*16 + (i>>2), phys kseg = i&3; global kseg = phys ^ ((row>>1)&3)
    int r0 = 2 * wave * 16 + (lane >> 2);
    int ksl = (lane & 3) ^ ((r0 >> 1) & 3);            // same for r0 and r0+16
    const bf16* ga0 = A + (size_t)(m0 + r0) * K + ksl * 8;
    const bf16* gb0 = Bt + (size_t)(n0 + r0) * K + ksl * 8;
    size_t rowK16 = (size_t)16 * K;
    bf16* la0 = &As[2 * wave * 512];
    bf16* la1 = &As[(2 * wave + 1) * 512];
    bf16* lb0 = &Bs[2 * wave * 512];
    bf16* lb1 = &Bs[(2 * wave + 1) * 512];

    for (int kb = 0; kb < K; kb += 32) {
        __syncthreads();                 // previous iteration's LDS reads complete
        async_ld16(ga0 + kb, la0);
        async_ld16(ga0 + rowK16 + kb, la1);
        async_ld16(gb0 + kb, lb0);
        async_ld16(gb0 + rowK16 + kb, lb1);
        __syncthreads();                 // vmcnt(0) drain + barrier: staged data visible

        bf16x8 af[4], bfv[4];
#pragma unroll
        for (int i = 0; i < 4; i++) {
            int ra = wm + i * 16 + lrow;
            af[i] = *(const bf16x8*)&As[ra * 32 + ((quad ^ ((ra >> 1) & 3)) << 3)];
            int rb = wn + i * 16 + lrow;
            bfv[i] = *(const bf16x8*)&Bs[rb * 32 + ((quad ^ ((rb >> 1) & 3)) << 3)];
        }
#pragma unroll
        for (int mi = 0; mi < 4; mi++)
#pragma unroll
            for (int ni = 0; ni < 4; ni++)
                acc[mi][ni] = __builtin_amdgcn_mfma_f32_16x16x32_bf16(
                    af[mi], bfv[ni], acc[mi][ni], 0, 0, 0);
    }

#pragma unroll
    for (int mi = 0; mi < 4; mi++) {
#pragma unroll
        for (int ni = 0; ni < 4; ni++) {
            int gn = n0 + wn + ni * 16 + lrow;
            float bv = 0.f;
            if (EPI == 1 || EPI == 3) bv = bias[gn];
#pragma unroll
            for (int r = 0; r < 4; r++) {
                int gm = m0 + wm + mi * 16 + quad * 4 + r;
                size_t off = (size_t)gm * N + gn;
                float val = acc[mi][ni][r];
                if (EPI == 0) {
                    Cout[off] = (bf16)val;
                } else if (EPI == 1) {
                    Cout[off] = (bf16)gelu_f(val + bv);
                } else if (EPI == 2) {
                    resid[off] += val;
                } else {
                    resid[off] += val + bv;
                }
            }
        }
    }
}

// ---------------- window attention: one block per (window, head) -------------------
__global__ __launch_bounds__(256) void k_attn(const bf16* __restrict__ qkv,
                                              const float* __restrict__ rpb,
                                              bf16* __restrict__ o) {
    int w = blockIdx.x;
    int hh = blockIdx.y;
    __shared__ float qs[49 * 32];
    __shared__ bf16 kst[32 * 52];        // transposed [d][j], padded to 52
    __shared__ bf16 vs[49 * 32];
    __shared__ float S[49][52];
    __shared__ float rpbs[169];
    int tid = threadIdx.x;
    const float scale = 0.17677669529663687f;  // 1/sqrt(32)
    const bf16* base = qkv + (size_t)w * 49 * 1152 + hh * 32;

    if (tid < 169) rpbs[tid] = rpb[tid * 12 + hh];
    for (int e = tid; e < 1568; e += 256) {
        int n = e >> 5, d = e & 31;
        size_t row = (size_t)n * 1152 + d;
        qs[e] = (float)base[row] * scale;
        kst[d * 52 + n] = base[row + 384];
        vs[e] = base[row + 768];
    }
    __syncthreads();

    // QK^T: items (i, jq), jq covers 4 columns
    for (int e = tid; e < 49 * 13; e += 256) {
        int i = e / 13, jq = e - i * 13;
        int j = jq * 4;
        float a[4] = {0.f, 0.f, 0.f, 0.f};
        const float* qp = qs + i * 32;
#pragma unroll 8
        for (int d = 0; d < 32; d++) {
            float qv = qp[d];
            bf16x4 kv = *(const bf16x4*)&kst[d * 52 + j];
#pragma unroll
            for (int t = 0; t < 4; t++) a[t] += qv * (float)kv[t];
        }
        int yi = i / 7, xi = i - yi * 7;
#pragma unroll
        for (int t = 0; t < 4; t++) {
            int j2 = j + t;
            if (j2 < 49) {
                int yj = j2 / 7, xj = j2 - yj * 7;
                int idx = (yi - yj + 6) * 13 + (xi - xj + 6);
                S[i][j2] = a[t] + rpbs[idx];
            }
        }
    }
    __syncthreads();

    if (tid < 49) {
        float m = -1e30f;
        for (int j = 0; j < 49; j++) m = fmaxf(m, S[tid][j]);
        float sum = 0.f;
        for (int j = 0; j < 49; j++) {
            float e2 = __expf(S[tid][j] - m);
            S[tid][j] = e2;
            sum += e2;
        }
        float inv = 1.f / sum;
        for (int j = 0; j < 49; j++) S[tid][j] *= inv;
    }
    __syncthreads();

    // PV: items (i, dq), dq covers 4 dims
    bf16* ob = o + (size_t)w * 49 * 384 + hh * 32;
    for (int e = tid; e < 49 * 8; e += 256) {
        int i = e >> 3, dq = e & 7;
        int d = dq * 4;
        float a[4] = {0.f, 0.f, 0.f, 0.f};
        for (int j = 0; j < 49; j++) {
            float sv = S[i][j];
            bf16x4 vv = *(const bf16x4*)&vs[j * 32 + d];
#pragma unroll
            for (int t = 0; t < 4; t++) a[t] += sv * (float)vv[t];
        }
        bf16x4 ov;
#pragma unroll
        for (int t = 0; t < 4; t++) ov[t] = (bf16)a[t];
        *(bf16x4*)&ob[(size_t)i * 384 + d] = ov;
    }
}

// ---------------- launch ----------------
extern "C" void kernel_launch(void* const* d_in, const int* in_sizes, int n_in,
                              void* d_out, int out_size, void* d_ws, size_t ws_size,
                              hipStream_t stream) {
    const float* x      = (const float*)d_in[0];
    const float* ln1_s  = (const float*)d_in[1];
    const float* ln1_b  = (const float*)d_in[2];
    const float* qkv_w  = (const float*)d_in[3];
    const float* rpb    = (const float*)d_in[4];
    const float* proj_w = (const float*)d_in[5];
    const float* ln2_s  = (const float*)d_in[6];
    const float* ln2_b  = (const float*)d_in[7];
    const float* mlp_w1 = (const float*)d_in[8];
    const float* mlp_b1 = (const float*)d_in[9];
    const float* mlp_w2 = (const float*)d_in[10];
    const float* mlp_b2 = (const float*)d_in[11];
    float* out = (float*)d_out;

    char* ws = (char*)d_ws;
    float* xres  = (float*)ws;                     // 77,070,336 B
    bf16* qkvbuf = (bf16*)(ws + 77070336);         // 115,605,504 B
    bf16* obuf   = (bf16*)(ws + 192675840);        // 38,535,168 B
    bf16* wbuf   = (bf16*)(ws + 231211008);        // 7,077,888 B (total 238,288,896)
    bf16* hidden = qkvbuf;                         // aliases qkv+obuf (154,140,672 B)
    bf16* hbuf   = (bf16*)d_out;                   // 38.5 MB scratch inside 77 MB out

    bf16* qkvw_b  = wbuf;                 // 884,736 elems  (2 layers, transposed [N][K])
    bf16* projw_b = wbuf + 884736;        // 294,912
    bf16* mlp1_b  = wbuf + 1179648;       // 1,179,648
    bf16* mlp2_b  = wbuf + 2359296;       // 1,179,648

    for (int l = 0; l < 2; l++) {
        k_f2bt<<<1728, 256, 0, stream>>>(qkv_w + (size_t)l * 442368,
                                         qkvw_b + (size_t)l * 442368, 384, 1152);
        k_f2bt<<<576, 256, 0, stream>>>(proj_w + (size_t)l * 147456,
                                        projw_b + (size_t)l * 147456, 384, 384);
        k_f2bt<<<2304, 256, 0, stream>>>(mlp_w1 + (size_t)l * 589824,
                                         mlp1_b + (size_t)l * 589824, 384, 1536);
        k_f2bt<<<2304, 256, 0, stream>>>(mlp_w2 + (size_t)l * 589824,
                                         mlp2_b + (size_t)l * 589824, 1536, 384);
    }

    k_reorder_in<<<18816, 256, 0, stream>>>((const float4*)x, (float4*)xres);

    for (int l = 0; l < 2; l++) {
        k_ln<<<12544, 256, 0, stream>>>(xres, ln1_s + l * 384, ln1_b + l * 384, hbuf);
        k_gemm<0><<<dim3(392, 9), 256, 0, stream>>>(
            hbuf, qkvw_b + (size_t)l * 442368, nullptr, nullptr, qkvbuf, 1152, 384);
        k_attn<<<dim3(1024, 12), 256, 0, stream>>>(qkvbuf, rpb + l * 169 * 12, obuf);
        k_gemm<2><<<dim3(392, 3), 256, 0, stream>>>(
            obuf, projw_b + (size_t)l * 147456, nullptr, xres, nullptr, 384, 384);
        k_ln<<<12544, 256, 0, stream>>>(xres, ln2_s + l * 384, ln2_b + l * 384, hbuf);
        k_gemm<1><<<dim3(392, 12), 256, 0, stream>>>(
            hbuf, mlp1_b + (size_t)l * 589824, mlp_b1 + l * 1536, nullptr, hidden, 1536, 384);
        k_gemm<3><<<dim3(392, 3), 256, 0, stream>>>(
            hidden, mlp2_b + (size_t)l * 589824, mlp_b2 + l * 384, xres, nullptr, 384, 1536);
    }

    k_reorder_out<<<18816, 256, 0, stream>>>((const float4*)xres, (float4*)out);
}

// Round 4
// 1311.462 us; speedup vs baseline: 1.2453x; 1.1183x over previous
//
#include <hip/hip_runtime.h>
#include <hip/hip_bf16.h>

typedef __bf16 bf16;
typedef __attribute__((ext_vector_type(4))) __bf16 bf16x4;
typedef __attribute__((ext_vector_type(8))) __bf16 bf16x8;
typedef __attribute__((ext_vector_type(4))) float f32x4;

// ---------------- async global->LDS helper (16B per lane, wave-uniform LDS base) ----
__device__ __forceinline__ void async_ld16(const void* g, void* l) {
    __builtin_amdgcn_global_load_lds(
        (const __attribute__((address_space(1))) unsigned int*)g,
        (__attribute__((address_space(3))) unsigned int*)l, 16, 0, 0);
}

// ---------------- fp32 -> bf16 transposed weight convert: in[K][N] -> out[N][K] ----
__global__ __launch_bounds__(256) void k_f2bt(const float* __restrict__ in,
                                              bf16* __restrict__ out, int Kd, int Nd) {
    int id = blockIdx.x * 256 + threadIdx.x;
    if (id >= Kd * Nd) return;
    int k = id / Nd, n = id - k * Nd;
    out[(size_t)n * Kd + k] = (bf16)in[id];
}

// ---------------- reorder: (B,H,W,C) fp32 <-> (win,tok,C) fp32, float4-wide --------
__global__ __launch_bounds__(256) void k_reorder_in(const float4* __restrict__ x,
                                                    float4* __restrict__ xres) {
    int id = blockIdx.x * 256 + threadIdx.x;          // 4,816,896 float4s
    int c4 = id % 96;
    int t = id / 96;
    int b = t / 3136;
    int rem = t - b * 3136;
    int y = rem / 56;
    int xc = rem - y * 56;
    int w = b * 64 + (y / 7) * 8 + (xc / 7);
    int n = (y % 7) * 7 + (xc % 7);
    xres[(size_t)(w * 49 + n) * 96 + c4] = x[id];
}

__global__ __launch_bounds__(256) void k_reorder_out(const float4* __restrict__ xres,
                                                     float4* __restrict__ out) {
    int id = blockIdx.x * 256 + threadIdx.x;
    int c4 = id % 96;
    int t = id / 96;
    int b = t / 3136;
    int rem = t - b * 3136;
    int y = rem / 56;
    int xc = rem - y * 56;
    int w = b * 64 + (y / 7) * 8 + (xc / 7);
    int n = (y % 7) * 7 + (xc % 7);
    out[id] = xres[(size_t)(w * 49 + n) * 96 + c4];
}

// ---------------- LayerNorm: fp32 residual -> bf16, float4-wide --------------------
__global__ __launch_bounds__(256) void k_ln(const float* __restrict__ xres,
                                            const float* __restrict__ s,
                                            const float* __restrict__ b,
                                            bf16* __restrict__ h) {
    int t = blockIdx.x * 4 + (threadIdx.x >> 6);
    int lane = threadIdx.x & 63;
    const float4* row = (const float4*)(xres + (size_t)t * 384);  // 96 float4
    float4 v0 = row[lane];
    float4 v1 = make_float4(0.f, 0.f, 0.f, 0.f);
    if (lane < 32) v1 = row[64 + lane];
    float sum = v0.x + v0.y + v0.z + v0.w + v1.x + v1.y + v1.z + v1.w;
#pragma unroll
    for (int m = 1; m < 64; m <<= 1) sum += __shfl_xor(sum, m);
    float mu = sum * (1.f / 384.f);
    float sq = (v0.x - mu) * (v0.x - mu) + (v0.y - mu) * (v0.y - mu) +
               (v0.z - mu) * (v0.z - mu) + (v0.w - mu) * (v0.w - mu);
    if (lane < 32)
        sq += (v1.x - mu) * (v1.x - mu) + (v1.y - mu) * (v1.y - mu) +
              (v1.z - mu) * (v1.z - mu) + (v1.w - mu) * (v1.w - mu);
#pragma unroll
    for (int m = 1; m < 64; m <<= 1) sq += __shfl_xor(sq, m);
    float r = rsqrtf(sq * (1.f / 384.f) + 1e-6f);
    const float4* s4 = (const float4*)s;
    const float4* b4 = (const float4*)b;
    bf16* ho = h + (size_t)t * 384;
    {
        float4 sv = s4[lane], bv = b4[lane];
        bf16x4 ov;
        ov[0] = (bf16)((v0.x - mu) * r * sv.x + bv.x);
        ov[1] = (bf16)((v0.y - mu) * r * sv.y + bv.y);
        ov[2] = (bf16)((v0.z - mu) * r * sv.z + bv.z);
        ov[3] = (bf16)((v0.w - mu) * r * sv.w + bv.w);
        *(bf16x4*)&ho[lane * 4] = ov;
    }
    if (lane < 32) {
        float4 sv = s4[64 + lane], bv = b4[64 + lane];
        bf16x4 ov;
        ov[0] = (bf16)((v1.x - mu) * r * sv.x + bv.x);
        ov[1] = (bf16)((v1.y - mu) * r * sv.y + bv.y);
        ov[2] = (bf16)((v1.z - mu) * r * sv.z + bv.z);
        ov[3] = (bf16)((v1.w - mu) * r * sv.w + bv.w);
        *(bf16x4*)&ho[256 + lane * 4] = ov;
    }
}

// ---------------- GELU (tanh approximation, matches jax.nn.gelu) -------------------
__device__ inline float gelu_f(float x) {
    float u = 0.7978845608028654f * (x + 0.044715f * x * x * x);
    float t = 1.f - 2.f / (__expf(2.f * u) + 1.f);
    return 0.5f * x * (1.f + t);
}

// ---------------- GEMM: C[M,N] = A[M,K] @ Bt[N,K]^T (+epilogue) --------------------
// EPI 0: store bf16 | 1: +bias, gelu, store bf16 | 2: add into fp32 resid | 3: +bias, add resid
// 128x128 tile, BK=64, 4 waves (2x2), global_load_lds staging, XOR kseg swizzle.
template <int EPI>
__global__ __launch_bounds__(256) void k_gemm(const bf16* __restrict__ A,
                                              const bf16* __restrict__ Bt,
                                              const float* __restrict__ bias,
                                              float* __restrict__ resid,
                                              bf16* __restrict__ Cout,
                                              int N, int K) {
    __shared__ __align__(16) bf16 As[128 * 64];   // 16 KB, [row][phys kseg*8]
    __shared__ __align__(16) bf16 Bs[128 * 64];   // 16 KB
    int tid = threadIdx.x;
    int m0 = blockIdx.x * 128;
    int n0 = blockIdx.y * 128;
    int wave = tid >> 6, lane = tid & 63;
    int wm = (wave >> 1) * 64, wn = (wave & 1) * 64;
    int lrow = lane & 15, quad = lane >> 4;

    f32x4 acc[4][4] = {};

    // staging: wave w handles rows [w*32, w*32+32) of A and B; chunk c = 8 rows.
    // lane -> row = c*8 + (lane>>3); phys kseg = lane&7; logical = phys ^ (row&7)
    int rsub = lane >> 3;                               // row & 7
    int ksl = ((lane & 7) ^ rsub) << 3;                 // element offset of logical kseg
    int rbase = wave * 32 + rsub;
    const bf16* ga = A + (size_t)(m0 + rbase) * K + ksl;
    const bf16* gb = Bt + (size_t)(n0 + rbase) * K + ksl;
    size_t row8 = (size_t)8 * K;
    bf16* lA = &As[wave * 32 * 64];
    bf16* lB = &Bs[wave * 32 * 64];

    for (int kb = 0; kb < K; kb += 64) {
        __syncthreads();                 // previous iteration's LDS reads complete
#pragma unroll
        for (int c = 0; c < 4; c++) {
            async_ld16(ga + c * row8 + kb, lA + c * 512);
            async_ld16(gb + c * row8 + kb, lB + c * 512);
        }
        __syncthreads();                 // vmcnt drain + barrier: staged data visible

        bf16x8 af[2][4], bfv[2][4];
#pragma unroll
        for (int kk = 0; kk < 2; kk++) {
#pragma unroll
            for (int i = 0; i < 4; i++) {
                int ra = wm + i * 16 + lrow;
                af[kk][i] = *(const bf16x8*)&As[ra * 64 + (((kk * 4 + quad) ^ (ra & 7)) << 3)];
                int rb = wn + i * 16 + lrow;
                bfv[kk][i] = *(const bf16x8*)&Bs[rb * 64 + (((kk * 4 + quad) ^ (rb & 7)) << 3)];
            }
        }
#pragma unroll
        for (int kk = 0; kk < 2; kk++)
#pragma unroll
            for (int mi = 0; mi < 4; mi++)
#pragma unroll
                for (int ni = 0; ni < 4; ni++)
                    acc[mi][ni] = __builtin_amdgcn_mfma_f32_16x16x32_bf16(
                        af[kk][mi], bfv[kk][ni], acc[mi][ni], 0, 0, 0);
    }

#pragma unroll
    for (int mi = 0; mi < 4; mi++) {
#pragma unroll
        for (int ni = 0; ni < 4; ni++) {
            int gn = n0 + wn + ni * 16 + lrow;
            float bv = 0.f;
            if (EPI == 1 || EPI == 3) bv = bias[gn];
#pragma unroll
            for (int r = 0; r < 4; r++) {
                int gm = m0 + wm + mi * 16 + quad * 4 + r;
                size_t off = (size_t)gm * N + gn;
                float val = acc[mi][ni][r];
                if (EPI == 0) {
                    Cout[off] = (bf16)val;
                } else if (EPI == 1) {
                    Cout[off] = (bf16)gelu_f(val + bv);
                } else if (EPI == 2) {
                    resid[off] += val;
                } else {
                    resid[off] += val + bv;
                }
            }
        }
    }
}

// ---------------- MFMA window attention: one WAVE per (window, head) ---------------
// grid (1024, 3) x 256 threads; head = blockIdx.y*4 + wave.
__global__ __launch_bounds__(256) void k_attn(const bf16* __restrict__ qkv,
                                              const float* __restrict__ rpb,
                                              bf16* __restrict__ o) {
    __shared__ unsigned short relIdx[2401];
    __shared__ float rpbs[4][169];
    __shared__ __align__(16) bf16 Vs[4][32 * 72];   // [d][j], stride 72
    __shared__ __align__(16) bf16 Ps[4][64 * 72];   // [i][j], stride 72

    int tid = threadIdx.x;
    int wave = tid >> 6, lane = tid & 63;
    int col = lane & 15, quad = lane >> 4;
    int w = blockIdx.x;
    int head = blockIdx.y * 4 + wave;
    const float scale = 0.17677669529663687f;  // 1/sqrt(32)

    // rel-pos index table (block-shared)
    for (int e = tid; e < 2401; e += 256) {
        int i = e / 49, j = e - i * 49;
        int yi = i / 7, xi = i - yi * 7, yj = j / 7, xj = j - yj * 7;
        relIdx[e] = (unsigned short)((yi - yj + 6) * 13 + (xi - xj + 6));
    }
    // per-wave rpb slice for this head
    for (int e = lane; e < 169; e += 64) rpbs[wave][e] = rpb[e * 12 + head];

    const bf16* base = qkv + (size_t)w * 49 * 1152 + head * 32;
    bf16* vsw = Vs[wave];
    bf16* psw = Ps[wave];

    // stage V transposed: Vs[d][j]; zero first (j>=49 pad must be exact 0)
    bf16x4 z4 = {(bf16)0.f, (bf16)0.f, (bf16)0.f, (bf16)0.f};
    for (int e = lane; e < 576; e += 64) *(bf16x4*)&vsw[e * 4] = z4;
    for (int e = lane; e < 392; e += 64) {          // 49 rows x 8 chunks of 4 d
        int j = e >> 3, d4 = (e & 7) * 4;
        bf16x4 vv = *(const bf16x4*)&base[768 + (size_t)j * 1152 + d4];
        vsw[(d4 + 0) * 72 + j] = vv[0];
        vsw[(d4 + 1) * 72 + j] = vv[1];
        vsw[(d4 + 2) * 72 + j] = vv[2];
        vsw[(d4 + 3) * 72 + j] = vv[3];
    }

    __syncthreads();   // relIdx ready for all waves

    // Q/K fragments direct from global (A: m=lane&15,k=quad*8; B: n=lane&15,k=quad*8)
    bf16x8 qf[4], kf[4];
#pragma unroll
    for (int mi = 0; mi < 4; mi++) {
        size_t row = (size_t)(mi * 16 + col) * 1152 + quad * 8;
        qf[mi] = *(const bf16x8*)&base[row];
        kf[mi] = *(const bf16x8*)&base[384 + row];
    }

    f32x4 S[4][4] = {};
#pragma unroll
    for (int mi = 0; mi < 4; mi++)
#pragma unroll
        for (int nj = 0; nj < 4; nj++)
            S[mi][nj] = __builtin_amdgcn_mfma_f32_16x16x32_bf16(qf[mi], kf[nj], S[mi][nj], 0, 0, 0);

    // softmax in registers: row i = mi*16+quad*4+r, col j = nj*16+col
    float* rp = rpbs[wave];
#pragma unroll
    for (int mi = 0; mi < 4; mi++) {
#pragma unroll
        for (int r = 0; r < 4; r++) {
            int ii = mi * 16 + quad * 4 + r;
            int ir = (ii < 49 ? ii : 0) * 49;
            float sv[4];
            float mx = -1e30f;
#pragma unroll
            for (int nj = 0; nj < 4; nj++) {
                int j = nj * 16 + col;
                float v;
                if (j < 49) v = S[mi][nj][r] * scale + rp[relIdx[ir + j]];
                else v = -1e30f;
                sv[nj] = v;
                mx = fmaxf(mx, v);
            }
#pragma unroll
            for (int m = 1; m < 16; m <<= 1) mx = fmaxf(mx, __shfl_xor(mx, m));
            float sum = 0.f;
#pragma unroll
            for (int nj = 0; nj < 4; nj++) {
                float p = __expf(sv[nj] - mx);   // masked cols -> exp(-huge) = 0
                sv[nj] = p;
                sum += p;
            }
#pragma unroll
            for (int m = 1; m < 16; m <<= 1) sum += __shfl_xor(sum, m);
            float is = 1.f / sum;
#pragma unroll
            for (int nj = 0; nj < 4; nj++)
                psw[ii * 72 + nj * 16 + col] = (bf16)(sv[nj] * is);
        }
    }

    __syncthreads();   // P, V visible (cross-lane LDS round-trip)

    // O = P @ V : A-frag from Ps, B-frag from Vs
    f32x4 O[4][2] = {};
#pragma unroll
    for (int kt = 0; kt < 2; kt++) {
        bf16x8 vb[2];
#pragma unroll
        for (int nt = 0; nt < 2; nt++)
            vb[nt] = *(const bf16x8*)&vsw[(nt * 16 + col) * 72 + kt * 32 + quad * 8];
#pragma unroll
        for (int mi = 0; mi < 4; mi++) {
            bf16x8 pa = *(const bf16x8*)&psw[(mi * 16 + col) * 72 + kt * 32 + quad * 8];
#pragma unroll
            for (int nt = 0; nt < 2; nt++)
                O[mi][nt] = __builtin_amdgcn_mfma_f32_16x16x32_bf16(pa, vb[nt], O[mi][nt], 0, 0, 0);
        }
    }

    bf16* ob = o + (size_t)w * 49 * 384 + head * 32;
#pragma unroll
    for (int mi = 0; mi < 4; mi++) {
#pragma unroll
        for (int r = 0; r < 4; r++) {
            int i = mi * 16 + quad * 4 + r;
            if (i < 49) {
#pragma unroll
                for (int nt = 0; nt < 2; nt++)
                    ob[(size_t)i * 384 + nt * 16 + col] = (bf16)O[mi][nt][r];
            }
        }
    }
}

// ---------------- launch ----------------
extern "C" void kernel_launch(void* const* d_in, const int* in_sizes, int n_in,
                              void* d_out, int out_size, void* d_ws, size_t ws_size,
                              hipStream_t stream) {
    const float* x      = (const float*)d_in[0];
    const float* ln1_s  = (const float*)d_in[1];
    const float* ln1_b  = (const float*)d_in[2];
    const float* qkv_w  = (const float*)d_in[3];
    const float* rpb    = (const float*)d_in[4];
    const float* proj_w = (const float*)d_in[5];
    const float* ln2_s  = (const float*)d_in[6];
    const float* ln2_b  = (const float*)d_in[7];
    const float* mlp_w1 = (const float*)d_in[8];
    const float* mlp_b1 = (const float*)d_in[9];
    const float* mlp_w2 = (const float*)d_in[10];
    const float* mlp_b2 = (const float*)d_in[11];
    float* out = (float*)d_out;

    char* ws = (char*)d_ws;
    float* xres  = (float*)ws;                     // 77,070,336 B
    bf16* qkvbuf = (bf16*)(ws + 77070336);         // 115,605,504 B
    bf16* obuf   = (bf16*)(ws + 192675840);        // 38,535,168 B
    bf16* wbuf   = (bf16*)(ws + 231211008);        // 7,077,888 B (total 238,288,896)
    bf16* hidden = qkvbuf;                         // aliases qkv+obuf (154,140,672 B)
    bf16* hbuf   = (bf16*)d_out;                   // 38.5 MB scratch inside 77 MB out

    bf16* qkvw_b  = wbuf;                 // 884,736 elems  (2 layers, transposed [N][K])
    bf16* projw_b = wbuf + 884736;        // 294,912
    bf16* mlp1_b  = wbuf + 1179648;       // 1,179,648
    bf16* mlp2_b  = wbuf + 2359296;       // 1,179,648

    for (int l = 0; l < 2; l++) {
        k_f2bt<<<1728, 256, 0, stream>>>(qkv_w + (size_t)l * 442368,
                                         qkvw_b + (size_t)l * 442368, 384, 1152);
        k_f2bt<<<576, 256, 0, stream>>>(proj_w + (size_t)l * 147456,
                                        projw_b + (size_t)l * 147456, 384, 384);
        k_f2bt<<<2304, 256, 0, stream>>>(mlp_w1 + (size_t)l * 589824,
                                         mlp1_b + (size_t)l * 589824, 384, 1536);
        k_f2bt<<<2304, 256, 0, stream>>>(mlp_w2 + (size_t)l * 589824,
                                         mlp2_b + (size_t)l * 589824, 1536, 384);
    }

    k_reorder_in<<<18816, 256, 0, stream>>>((const float4*)x, (float4*)xres);

    for (int l = 0; l < 2; l++) {
        k_ln<<<12544, 256, 0, stream>>>(xres, ln1_s + l * 384, ln1_b + l * 384, hbuf);
        k_gemm<0><<<dim3(392, 9), 256, 0, stream>>>(
            hbuf, qkvw_b + (size_t)l * 442368, nullptr, nullptr, qkvbuf, 1152, 384);
        k_attn<<<dim3(1024, 3), 256, 0, stream>>>(qkvbuf, rpb + l * 169 * 12, obuf);
        k_gemm<2><<<dim3(392, 3), 256, 0, stream>>>(
            obuf, projw_b + (size_t)l * 147456, nullptr, xres, nullptr, 384, 384);
        k_ln<<<12544, 256, 0, stream>>>(xres, ln2_s + l * 384, ln2_b + l * 384, hbuf);
        k_gemm<1><<<dim3(392, 12), 256, 0, stream>>>(
            hbuf, mlp1_b + (size_t)l * 589824, mlp_b1 + l * 1536, nullptr, hidden, 1536, 384);
        k_gemm<3><<<dim3(392, 3), 256, 0, stream>>>(
            hidden, mlp2_b + (size_t)l * 589824, mlp_b2 + l * 384, xres, nullptr, 384, 1536);
    }

    k_reorder_out<<<18816, 256, 0, stream>>>((const float4*)xres, (float4*)out);
}

// Round 5
// 1247.809 us; speedup vs baseline: 1.3088x; 1.0510x over previous
//
#include <hip/hip_runtime.h>
#include <hip/hip_bf16.h>

typedef __bf16 bf16;
typedef __attribute__((ext_vector_type(4))) __bf16 bf16x4;
typedef __attribute__((ext_vector_type(8))) __bf16 bf16x8;
typedef __attribute__((ext_vector_type(4))) float f32x4;

// ---------------- async global->LDS helper (16B per lane, wave-uniform LDS base) ----
__device__ __forceinline__ void async_ld16(const void* g, void* l) {
    __builtin_amdgcn_global_load_lds(
        (const __attribute__((address_space(1))) unsigned int*)g,
        (__attribute__((address_space(3))) unsigned int*)l, 16, 0, 0);
}

// ---------------- fp32 -> bf16 transposed weight convert: in[K][N] -> out[N][K] ----
__global__ __launch_bounds__(256) void k_f2bt(const float* __restrict__ in,
                                              bf16* __restrict__ out, int Kd, int Nd) {
    int id = blockIdx.x * 256 + threadIdx.x;
    if (id >= Kd * Nd) return;
    int k = id / Nd, n = id - k * Nd;
    out[(size_t)n * Kd + k] = (bf16)in[id];
}

// ---------------- reorder: (B,H,W,C) fp32 <-> (win,tok,C) fp32, float4-wide --------
__global__ __launch_bounds__(256) void k_reorder_in(const float4* __restrict__ x,
                                                    float4* __restrict__ xres) {
    int id = blockIdx.x * 256 + threadIdx.x;          // 4,816,896 float4s
    int c4 = id % 96;
    int t = id / 96;
    int b = t / 3136;
    int rem = t - b * 3136;
    int y = rem / 56;
    int xc = rem - y * 56;
    int w = b * 64 + (y / 7) * 8 + (xc / 7);
    int n = (y % 7) * 7 + (xc % 7);
    xres[(size_t)(w * 49 + n) * 96 + c4] = x[id];
}

__global__ __launch_bounds__(256) void k_reorder_out(const float4* __restrict__ xres,
                                                     float4* __restrict__ out) {
    int id = blockIdx.x * 256 + threadIdx.x;
    int c4 = id % 96;
    int t = id / 96;
    int b = t / 3136;
    int rem = t - b * 3136;
    int y = rem / 56;
    int xc = rem - y * 56;
    int w = b * 64 + (y / 7) * 8 + (xc / 7);
    int n = (y % 7) * 7 + (xc % 7);
    out[id] = xres[(size_t)(w * 49 + n) * 96 + c4];
}

// ---------------- LayerNorm: fp32 residual -> bf16, float4-wide --------------------
__global__ __launch_bounds__(256) void k_ln(const float* __restrict__ xres,
                                            const float* __restrict__ s,
                                            const float* __restrict__ b,
                                            bf16* __restrict__ h) {
    int t = blockIdx.x * 4 + (threadIdx.x >> 6);
    int lane = threadIdx.x & 63;
    const float4* row = (const float4*)(xres + (size_t)t * 384);  // 96 float4
    float4 v0 = row[lane];
    float4 v1 = make_float4(0.f, 0.f, 0.f, 0.f);
    if (lane < 32) v1 = row[64 + lane];
    float sum = v0.x + v0.y + v0.z + v0.w + v1.x + v1.y + v1.z + v1.w;
#pragma unroll
    for (int m = 1; m < 64; m <<= 1) sum += __shfl_xor(sum, m);
    float mu = sum * (1.f / 384.f);
    float sq = (v0.x - mu) * (v0.x - mu) + (v0.y - mu) * (v0.y - mu) +
               (v0.z - mu) * (v0.z - mu) + (v0.w - mu) * (v0.w - mu);
    if (lane < 32)
        sq += (v1.x - mu) * (v1.x - mu) + (v1.y - mu) * (v1.y - mu) +
              (v1.z - mu) * (v1.z - mu) + (v1.w - mu) * (v1.w - mu);
#pragma unroll
    for (int m = 1; m < 64; m <<= 1) sq += __shfl_xor(sq, m);
    float r = rsqrtf(sq * (1.f / 384.f) + 1e-6f);
    const float4* s4 = (const float4*)s;
    const float4* b4 = (const float4*)b;
    bf16* ho = h + (size_t)t * 384;
    {
        float4 sv = s4[lane], bv = b4[lane];
        bf16x4 ov;
        ov[0] = (bf16)((v0.x - mu) * r * sv.x + bv.x);
        ov[1] = (bf16)((v0.y - mu) * r * sv.y + bv.y);
        ov[2] = (bf16)((v0.z - mu) * r * sv.z + bv.z);
        ov[3] = (bf16)((v0.w - mu) * r * sv.w + bv.w);
        *(bf16x4*)&ho[lane * 4] = ov;
    }
    if (lane < 32) {
        float4 sv = s4[64 + lane], bv = b4[64 + lane];
        bf16x4 ov;
        ov[0] = (bf16)((v1.x - mu) * r * sv.x + bv.x);
        ov[1] = (bf16)((v1.y - mu) * r * sv.y + bv.y);
        ov[2] = (bf16)((v1.z - mu) * r * sv.z + bv.z);
        ov[3] = (bf16)((v1.w - mu) * r * sv.w + bv.w);
        *(bf16x4*)&ho[256 + lane * 4] = ov;
    }
}

// ---------------- GELU (tanh approximation, matches jax.nn.gelu) -------------------
__device__ inline float gelu_f(float x) {
    float u = 0.7978845608028654f * (x + 0.044715f * x * x * x);
    float t = 1.f - 2.f / (__expf(2.f * u) + 1.f);
    return 0.5f * x * (1.f + t);
}

// ---------------- GEMM: C[M,N] = A[M,K] @ Bt[N,K]^T (+epilogue) --------------------
// EPI 0: store bf16 | 1: +bias, gelu, store bf16 | 2: add into fp32 resid | 3: +bias, add resid
// 128x128 tile, BK=32, 4 waves (2x2), global_load_lds staging, XOR kseg swizzle.
// Grid: (n_blocks, m_blocks) -- n fast-varying so blocks sharing an A-tile co-run.
// Epilogue: per-wave LDS transpose -> each lane stores 8 consecutive n (16B).
template <int EPI>
__global__ __launch_bounds__(256) void k_gemm(const bf16* __restrict__ A,
                                              const bf16* __restrict__ Bt,
                                              const float* __restrict__ bias,
                                              float* __restrict__ resid,
                                              bf16* __restrict__ Cout,
                                              int N, int K) {
    __shared__ __align__(16) char lds[17408];
    bf16* As = (bf16*)lds;                 // 128x32 bf16 = 8192 B, swizzled ksegs
    bf16* Bs = (bf16*)(lds + 8192);        // 128x32 bf16 = 8192 B
    int tid = threadIdx.x;
    int n0 = blockIdx.x * 128;
    int m0 = blockIdx.y * 128;
    int wave = tid >> 6, lane = tid & 63;
    int wm = (wave >> 1) * 64, wn = (wave & 1) * 64;
    int col = lane & 15, quad = lane >> 4;

    f32x4 acc[4][4] = {};

    // staging: wave w covers 16-row chunks 2w, 2w+1 of both A and B.
    // lane -> row = chunk*16 + (lane>>2); phys kseg = lane&3; logical = phys ^ ((row>>1)&3)
    int r0 = 2 * wave * 16 + (lane >> 2);
    int ksl = (lane & 3) ^ ((r0 >> 1) & 3);            // same for r0 and r0+16
    const bf16* ga0 = A + (size_t)(m0 + r0) * K + ksl * 8;
    const bf16* gb0 = Bt + (size_t)(n0 + r0) * K + ksl * 8;
    size_t rowK16 = (size_t)16 * K;
    bf16* la0 = &As[2 * wave * 512];
    bf16* la1 = &As[(2 * wave + 1) * 512];
    bf16* lb0 = &Bs[2 * wave * 512];
    bf16* lb1 = &Bs[(2 * wave + 1) * 512];

    for (int kb = 0; kb < K; kb += 32) {
        __syncthreads();                 // previous iteration's LDS reads complete
        async_ld16(ga0 + kb, la0);
        async_ld16(ga0 + rowK16 + kb, la1);
        async_ld16(gb0 + kb, lb0);
        async_ld16(gb0 + rowK16 + kb, lb1);
        __syncthreads();                 // vmcnt drain + barrier: staged data visible

        bf16x8 af[4], bfv[4];
#pragma unroll
        for (int i = 0; i < 4; i++) {
            int ra = wm + i * 16 + col;
            af[i] = *(const bf16x8*)&As[ra * 32 + ((quad ^ ((ra >> 1) & 3)) << 3)];
            int rb = wn + i * 16 + col;
            bfv[i] = *(const bf16x8*)&Bs[rb * 32 + ((quad ^ ((rb >> 1) & 3)) << 3)];
        }
#pragma unroll
        for (int mi = 0; mi < 4; mi++)
#pragma unroll
            for (int ni = 0; ni < 4; ni++)
                acc[mi][ni] = __builtin_amdgcn_mfma_f32_16x16x32_bf16(
                    af[mi], bfv[ni], acc[mi][ni], 0, 0, 0);
    }

    __syncthreads();   // all waves done with As/Bs; LDS becomes epilogue scratch
    float* scrw = (float*)lds + wave * (16 * 68);   // 16 rows x 68 stride, per wave

    int prow = lane >> 3;          // 0..7
    int pc0 = (lane & 7) * 8;      // 0,8,..,56
#pragma unroll
    for (int mi = 0; mi < 4; mi++) {
        // phase A: C-frag (col=lane&15, row=quad*4+r) -> scratch[row][col]
#pragma unroll
        for (int ni = 0; ni < 4; ni++)
#pragma unroll
            for (int r = 0; r < 4; r++)
                scrw[(quad * 4 + r) * 68 + ni * 16 + col] = acc[mi][ni][r];
        // phase B: lane -> row=h*8+prow, cols pc0..pc0+7 (contiguous n)
#pragma unroll
        for (int h = 0; h < 2; h++) {
            int lr = h * 8 + prow;
            const float* sp = scrw + lr * 68 + pc0;
            float4 u0 = *(const float4*)sp;
            float4 u1 = *(const float4*)(sp + 4);
            int gm = m0 + wm + mi * 16 + lr;
            int gn = n0 + wn + pc0;
            size_t off = (size_t)gm * N + gn;
            if (EPI == 0) {
                bf16x8 ov;
                ov[0] = (bf16)u0.x; ov[1] = (bf16)u0.y; ov[2] = (bf16)u0.z; ov[3] = (bf16)u0.w;
                ov[4] = (bf16)u1.x; ov[5] = (bf16)u1.y; ov[6] = (bf16)u1.z; ov[7] = (bf16)u1.w;
                *(bf16x8*)&Cout[off] = ov;
            } else if (EPI == 1) {
                float4 b0 = *(const float4*)&bias[gn];
                float4 b1 = *(const float4*)&bias[gn + 4];
                bf16x8 ov;
                ov[0] = (bf16)gelu_f(u0.x + b0.x); ov[1] = (bf16)gelu_f(u0.y + b0.y);
                ov[2] = (bf16)gelu_f(u0.z + b0.z); ov[3] = (bf16)gelu_f(u0.w + b0.w);
                ov[4] = (bf16)gelu_f(u1.x + b1.x); ov[5] = (bf16)gelu_f(u1.y + b1.y);
                ov[6] = (bf16)gelu_f(u1.z + b1.z); ov[7] = (bf16)gelu_f(u1.w + b1.w);
                *(bf16x8*)&Cout[off] = ov;
            } else if (EPI == 2) {
                float4 r0v = *(const float4*)&resid[off];
                float4 r1v = *(const float4*)&resid[off + 4];
                r0v.x += u0.x; r0v.y += u0.y; r0v.z += u0.z; r0v.w += u0.w;
                r1v.x += u1.x; r1v.y += u1.y; r1v.z += u1.z; r1v.w += u1.w;
                *(float4*)&resid[off] = r0v;
                *(float4*)&resid[off + 4] = r1v;
            } else {
                float4 b0 = *(const float4*)&bias[gn];
                float4 b1 = *(const float4*)&bias[gn + 4];
                float4 r0v = *(const float4*)&resid[off];
                float4 r1v = *(const float4*)&resid[off + 4];
                r0v.x += u0.x + b0.x; r0v.y += u0.y + b0.y;
                r0v.z += u0.z + b0.z; r0v.w += u0.w + b0.w;
                r1v.x += u1.x + b1.x; r1v.y += u1.y + b1.y;
                r1v.z += u1.z + b1.z; r1v.w += u1.w + b1.w;
                *(float4*)&resid[off] = r0v;
                *(float4*)&resid[off + 4] = r1v;
            }
        }
    }
}

// ---------------- MFMA window attention: one WAVE per (window, head) ---------------
// grid (1024, 3) x 256 threads; head = blockIdx.y*4 + wave.
__global__ __launch_bounds__(256) void k_attn(const bf16* __restrict__ qkv,
                                              const float* __restrict__ rpb,
                                              bf16* __restrict__ o) {
    __shared__ unsigned short relIdx[2401];
    __shared__ float rpbs[4][169];
    __shared__ __align__(16) bf16 Vs[4][32 * 72];   // [d][j], stride 72
    __shared__ __align__(16) bf16 Ps[4][64 * 72];   // [i][j], stride 72

    int tid = threadIdx.x;
    int wave = tid >> 6, lane = tid & 63;
    int col = lane & 15, quad = lane >> 4;
    int w = blockIdx.x;
    int head = blockIdx.y * 4 + wave;
    const float scale = 0.17677669529663687f;  // 1/sqrt(32)

    for (int e = tid; e < 2401; e += 256) {
        int i = e / 49, j = e - i * 49;
        int yi = i / 7, xi = i - yi * 7, yj = j / 7, xj = j - yj * 7;
        relIdx[e] = (unsigned short)((yi - yj + 6) * 13 + (xi - xj + 6));
    }
    for (int e = lane; e < 169; e += 64) rpbs[wave][e] = rpb[e * 12 + head];

    const bf16* base = qkv + (size_t)w * 49 * 1152 + head * 32;
    bf16* vsw = Vs[wave];
    bf16* psw = Ps[wave];

    bf16x4 z4 = {(bf16)0.f, (bf16)0.f, (bf16)0.f, (bf16)0.f};
    for (int e = lane; e < 576; e += 64) *(bf16x4*)&vsw[e * 4] = z4;
    for (int e = lane; e < 392; e += 64) {          // 49 rows x 8 chunks of 4 d
        int j = e >> 3, d4 = (e & 7) * 4;
        bf16x4 vv = *(const bf16x4*)&base[768 + (size_t)j * 1152 + d4];
        vsw[(d4 + 0) * 72 + j] = vv[0];
        vsw[(d4 + 1) * 72 + j] = vv[1];
        vsw[(d4 + 2) * 72 + j] = vv[2];
        vsw[(d4 + 3) * 72 + j] = vv[3];
    }

    __syncthreads();   // relIdx ready for all waves

    bf16x8 qf[4], kf[4];
#pragma unroll
    for (int mi = 0; mi < 4; mi++) {
        size_t row = (size_t)(mi * 16 + col) * 1152 + quad * 8;
        qf[mi] = *(const bf16x8*)&base[row];
        kf[mi] = *(const bf16x8*)&base[384 + row];
    }

    f32x4 S[4][4] = {};
#pragma unroll
    for (int mi = 0; mi < 4; mi++)
#pragma unroll
        for (int nj = 0; nj < 4; nj++)
            S[mi][nj] = __builtin_amdgcn_mfma_f32_16x16x32_bf16(qf[mi], kf[nj], S[mi][nj], 0, 0, 0);

    float* rp = rpbs[wave];
#pragma unroll
    for (int mi = 0; mi < 4; mi++) {
#pragma unroll
        for (int r = 0; r < 4; r++) {
            int ii = mi * 16 + quad * 4 + r;
            int ir = (ii < 49 ? ii : 0) * 49;
            float sv[4];
            float mx = -1e30f;
#pragma unroll
            for (int nj = 0; nj < 4; nj++) {
                int j = nj * 16 + col;
                float v;
                if (j < 49) v = S[mi][nj][r] * scale + rp[relIdx[ir + j]];
                else v = -1e30f;
                sv[nj] = v;
                mx = fmaxf(mx, v);
            }
#pragma unroll
            for (int m = 1; m < 16; m <<= 1) mx = fmaxf(mx, __shfl_xor(mx, m));
            float sum = 0.f;
#pragma unroll
            for (int nj = 0; nj < 4; nj++) {
                float p = __expf(sv[nj] - mx);
                sv[nj] = p;
                sum += p;
            }
#pragma unroll
            for (int m = 1; m < 16; m <<= 1) sum += __shfl_xor(sum, m);
            float is = 1.f / sum;
#pragma unroll
            for (int nj = 0; nj < 4; nj++)
                psw[ii * 72 + nj * 16 + col] = (bf16)(sv[nj] * is);
        }
    }

    __syncthreads();   // P, V visible

    f32x4 O[4][2] = {};
#pragma unroll
    for (int kt = 0; kt < 2; kt++) {
        bf16x8 vb[2];
#pragma unroll
        for (int nt = 0; nt < 2; nt++)
            vb[nt] = *(const bf16x8*)&vsw[(nt * 16 + col) * 72 + kt * 32 + quad * 8];
#pragma unroll
        for (int mi = 0; mi < 4; mi++) {
            bf16x8 pa = *(const bf16x8*)&psw[(mi * 16 + col) * 72 + kt * 32 + quad * 8];
#pragma unroll
            for (int nt = 0; nt < 2; nt++)
                O[mi][nt] = __builtin_amdgcn_mfma_f32_16x16x32_bf16(pa, vb[nt], O[mi][nt], 0, 0, 0);
        }
    }

    bf16* ob = o + (size_t)w * 49 * 384 + head * 32;
#pragma unroll
    for (int mi = 0; mi < 4; mi++) {
#pragma unroll
        for (int r = 0; r < 4; r++) {
            int i = mi * 16 + quad * 4 + r;
            if (i < 49) {
#pragma unroll
                for (int nt = 0; nt < 2; nt++)
                    ob[(size_t)i * 384 + nt * 16 + col] = (bf16)O[mi][nt][r];
            }
        }
    }
}

// ---------------- launch ----------------
extern "C" void kernel_launch(void* const* d_in, const int* in_sizes, int n_in,
                              void* d_out, int out_size, void* d_ws, size_t ws_size,
                              hipStream_t stream) {
    const float* x      = (const float*)d_in[0];
    const float* ln1_s  = (const float*)d_in[1];
    const float* ln1_b  = (const float*)d_in[2];
    const float* qkv_w  = (const float*)d_in[3];
    const float* rpb    = (const float*)d_in[4];
    const float* proj_w = (const float*)d_in[5];
    const float* ln2_s  = (const float*)d_in[6];
    const float* ln2_b  = (const float*)d_in[7];
    const float* mlp_w1 = (const float*)d_in[8];
    const float* mlp_b1 = (const float*)d_in[9];
    const float* mlp_w2 = (const float*)d_in[10];
    const float* mlp_b2 = (const float*)d_in[11];
    float* out = (float*)d_out;

    char* ws = (char*)d_ws;
    float* xres  = (float*)ws;                     // 77,070,336 B
    bf16* qkvbuf = (bf16*)(ws + 77070336);         // 115,605,504 B
    bf16* obuf   = (bf16*)(ws + 192675840);        // 38,535,168 B
    bf16* wbuf   = (bf16*)(ws + 231211008);        // 7,077,888 B (total 238,288,896)
    bf16* hidden = qkvbuf;                         // aliases qkv+obuf (154,140,672 B)
    bf16* hbuf   = (bf16*)d_out;                   // 38.5 MB scratch inside 77 MB out

    bf16* qkvw_b  = wbuf;                 // 884,736 elems  (2 layers, transposed [N][K])
    bf16* projw_b = wbuf + 884736;        // 294,912
    bf16* mlp1_b  = wbuf + 1179648;       // 1,179,648
    bf16* mlp2_b  = wbuf + 2359296;       // 1,179,648

    for (int l = 0; l < 2; l++) {
        k_f2bt<<<1728, 256, 0, stream>>>(qkv_w + (size_t)l * 442368,
                                         qkvw_b + (size_t)l * 442368, 384, 1152);
        k_f2bt<<<576, 256, 0, stream>>>(proj_w + (size_t)l * 147456,
                                        projw_b + (size_t)l * 147456, 384, 384);
        k_f2bt<<<2304, 256, 0, stream>>>(mlp_w1 + (size_t)l * 589824,
                                         mlp1_b + (size_t)l * 589824, 384, 1536);
        k_f2bt<<<2304, 256, 0, stream>>>(mlp_w2 + (size_t)l * 589824,
                                         mlp2_b + (size_t)l * 589824, 1536, 384);
    }

    k_reorder_in<<<18816, 256, 0, stream>>>((const float4*)x, (float4*)xres);

    for (int l = 0; l < 2; l++) {
        k_ln<<<12544, 256, 0, stream>>>(xres, ln1_s + l * 384, ln1_b + l * 384, hbuf);
        k_gemm<0><<<dim3(9, 392), 256, 0, stream>>>(
            hbuf, qkvw_b + (size_t)l * 442368, nullptr, nullptr, qkvbuf, 1152, 384);
        k_attn<<<dim3(1024, 3), 256, 0, stream>>>(qkvbuf, rpb + l * 169 * 12, obuf);
        k_gemm<2><<<dim3(3, 392), 256, 0, stream>>>(
            obuf, projw_b + (size_t)l * 147456, nullptr, xres, nullptr, 384, 384);
        k_ln<<<12544, 256, 0, stream>>>(xres, ln2_s + l * 384, ln2_b + l * 384, hbuf);
        k_gemm<1><<<dim3(12, 392), 256, 0, stream>>>(
            hbuf, mlp1_b + (size_t)l * 589824, mlp_b1 + l * 1536, nullptr, hidden, 1536, 384);
        k_gemm<3><<<dim3(3, 392), 256, 0, stream>>>(
            hidden, mlp2_b + (size_t)l * 589824, mlp_b2 + l * 384, xres, nullptr, 384, 1536);
    }

    k_reorder_out<<<18816, 256, 0, stream>>>((const float4*)xres, (float4*)out);
}